// Round 14
// baseline (201.694 us; speedup 1.0000x reference)
//
#include <hip/hip_runtime.h>

#define NN 384
#define RR 8
#define NR (NN * RR)   // 3072
#define IPADH 193      // padded il-stride (192 + 1) breaks c-dim bank aliasing
#define GSTR 72        // Gh row stride in f16 (144B rows -> bank spread)

typedef _Float16 half4v __attribute__((ext_vector_type(4)));
typedef _Float16 half8v __attribute__((ext_vector_type(8)));
typedef float f32x4 __attribute__((ext_vector_type(4)));

// out[b,i] = sum_{a,b2,c} A[a,i,b2]*Bf[b2,j_b,c]*C[c,k_b,a]
// G[b2,a] = sum_c Bf[b2,j,c]*C[c,k,a];  out[b,i] = sum_p A2[i,p]*G[p], p=a*8+b2.
// r14 = r13 (proven 16x16x16_f16 MFMA epilogue, classic fragment maps) with
// i-halved blocks: 256 pairs x 192 i, LDS 33.9KB -> 4 blocks/CU, 32 waves/CU.
__global__ __launch_bounds__(512, 8)
void dtn_mfma16h(const float* __restrict__ A, const float* __restrict__ Bf,
                 const float* __restrict__ C, const int* __restrict__ x,
                 float* __restrict__ out)
{
    __shared__ __align__(16) _Float16 A2c[8 * IPADH * 8];  // 24704 B
    __shared__ __align__(16) _Float16 Gh[64 * GSTR];       //  9216 B

    const int t  = threadIdx.x;
    const int pbk = blockIdx.x >> 1;
    const int ih  = blockIdx.x & 1;          // i-half: [0,192) or [192,384)
    const long b0 = (long)pbk * 256;

    // ---- Stage this i-half of A2: A2c[(c*IPADH+il)*8+e] = f16(A2[ih*192+il][8c+e]).
    // A2 chunk (c, i) lives at A + (c*NN + i)*8  (identity layout of A).
    #pragma unroll
    for (int it = 0; it < 3; ++it) {
        const int L = it * 512 + t;          // 0..1535
        const int c = L / 192;
        const int il = L - c * 192;
        const float4* src = reinterpret_cast<const float4*>(A) + 2 * (c * NN + ih * 192 + il);
        const float4 f0 = src[0];
        const float4 f1 = src[1];
        half8v h;
        h[0] = (_Float16)f0.x; h[1] = (_Float16)f0.y; h[2] = (_Float16)f0.z; h[3] = (_Float16)f0.w;
        h[4] = (_Float16)f1.x; h[5] = (_Float16)f1.y; h[6] = (_Float16)f1.z; h[7] = (_Float16)f1.w;
        *reinterpret_cast<half8v*>(&A2c[(size_t)(c * IPADH + il) * 8]) = h;
    }

    const int lane = t & 63;
    const int w    = t >> 6;     // wave 0..7
    const int mt   = w & 3;      // M-tile (16 pairs) within the 64-pair batch
    const int nh2  = w >> 2;     // n-quarter within this half: [0,96) or [96,192)
    const int a16  = lane & 15;
    const int q    = lane >> 4;  // 0..3

    #pragma unroll 1
    for (int bt = 0; bt < 4; ++bt) {
        __syncthreads();   // Gh free to overwrite (also covers staging on bt=0)

        // ---- G phase (math identical to proven r10/r13): thread -> (bl=t>>3, a=t&7)
        {
            const int bl = t >> 3;
            const int a  = t & 7;
            const long pair = b0 + bt * 64 + bl;
            const int j = x[2 * pair];
            const int k = x[2 * pair + 1];
            const float* Bj = Bf + (size_t)j * RR;       // Bf[b2,j,c] at Bj[b2*NR + c]
            const float* Ck = C + (size_t)k * RR + a;    // C[c,k,a]   at Ck[c*NR]
            float ck[8];
            #pragma unroll
            for (int c = 0; c < 8; ++c)
                ck[c] = Ck[(size_t)c * NR];
            half8v h;
            #pragma unroll
            for (int b2 = 0; b2 < 8; ++b2) {
                const float4* br = reinterpret_cast<const float4*>(Bj + (size_t)b2 * NR);
                const float4 r0 = br[0];
                const float4 r1 = br[1];
                const float s = r0.x * ck[0] + r0.y * ck[1] + r0.z * ck[2] + r0.w * ck[3]
                              + r1.x * ck[4] + r1.y * ck[5] + r1.z * ck[6] + r1.w * ck[7];
                h[b2] = (_Float16)s;
            }
            *reinterpret_cast<half8v*>(&Gh[bl * GSTR + a * 8]) = h;   // p = a*8 + b2
        }
        __syncthreads();

        // ---- A-fragments: row = mt*16+a16, k-windows 0/16/32/48 (+4q within).
        const half4v af0 = *reinterpret_cast<const half4v*>(&Gh[(mt * 16 + a16) * GSTR +  0 + 4 * q]);
        const half4v af1 = *reinterpret_cast<const half4v*>(&Gh[(mt * 16 + a16) * GSTR + 16 + 4 * q]);
        const half4v af2 = *reinterpret_cast<const half4v*>(&Gh[(mt * 16 + a16) * GSTR + 32 + 4 * q]);
        const half4v af3 = *reinterpret_cast<const half4v*>(&Gh[(mt * 16 + a16) * GSTR + 48 + 4 * q]);

        const long prow0 = b0 + bt * 64 + mt * 16 + 4 * q;   // D row base for this lane

        // ---- 6 N-tiles of 16 i; B-frag: A2[il=n0+a16][k=16kt+4q+e]
        //      p = 16kt+4q+e -> chunk c = 2kt+(q>>1), elem = 4*(q&1)+e.
        #pragma unroll 2
        for (int nt = 0; nt < 6; ++nt) {
            const int il = nh2 * 96 + nt * 16 + a16;
            const int colg = ih * 192 + il;
            f32x4 acc = {0.f, 0.f, 0.f, 0.f};
            const half4v bf0 = *reinterpret_cast<const half4v*>(
                &A2c[(size_t)((0 + (q >> 1)) * IPADH + il) * 8 + 4 * (q & 1)]);
            acc = __builtin_amdgcn_mfma_f32_16x16x16f16(af0, bf0, acc, 0, 0, 0);
            const half4v bf1 = *reinterpret_cast<const half4v*>(
                &A2c[(size_t)((2 + (q >> 1)) * IPADH + il) * 8 + 4 * (q & 1)]);
            acc = __builtin_amdgcn_mfma_f32_16x16x16f16(af1, bf1, acc, 0, 0, 0);
            const half4v bf2 = *reinterpret_cast<const half4v*>(
                &A2c[(size_t)((4 + (q >> 1)) * IPADH + il) * 8 + 4 * (q & 1)]);
            acc = __builtin_amdgcn_mfma_f32_16x16x16f16(af2, bf2, acc, 0, 0, 0);
            const half4v bf3 = *reinterpret_cast<const half4v*>(
                &A2c[(size_t)((6 + (q >> 1)) * IPADH + il) * 8 + 4 * (q & 1)]);
            acc = __builtin_amdgcn_mfma_f32_16x16x16f16(af3, bf3, acc, 0, 0, 0);

            float* op = out + (size_t)prow0 * NN + colg;
            op[0]            = acc[0];
            op[(size_t)NN]   = acc[1];
            op[(size_t)2*NN] = acc[2];
            op[(size_t)3*NN] = acc[3];
        }
    }
}

extern "C" void kernel_launch(void* const* d_in, const int* in_sizes, int n_in,
                              void* d_out, int out_size, void* d_ws, size_t ws_size,
                              hipStream_t stream) {
    const float* A  = (const float*)d_in[0];
    const float* Bf = (const float*)d_in[1];
    const float* C  = (const float*)d_in[2];
    const int*   x  = (const int*)d_in[3];
    float* out = (float*)d_out;
    const int B = in_sizes[3] / 2;           // 524288
    dtn_mfma16h<<<(B / 256) * 2, 512, 0, stream>>>(A, Bf, C, x, out);
}

// Round 15
// 182.613 us; speedup vs baseline: 1.1045x; 1.1045x over previous
//
#include <hip/hip_runtime.h>

#define NN 384
#define RR 8
#define NR (NN * RR)   // 3072
#define IPAD 385       // padded i-stride for A2c (breaks c-dimension bank aliasing)
#define GSTR 72        // Gh row stride in f16 (144B rows -> bank spread)

typedef _Float16 half4v __attribute__((ext_vector_type(4)));
typedef _Float16 half8v __attribute__((ext_vector_type(8)));
typedef float f32x4 __attribute__((ext_vector_type(4)));

// out[b,i] = sum_{a,b2,c} A[a,i,b2]*Bf[b2,j_b,c]*C[c,k_b,a]
// G[b2,a] = sum_c Bf[b2,j,c]*C[c,k,a];  out[b,i] = sum_p A2[i,p]*G[p], p=a*8+b2.
// r15 = r13 (proven 16x16x16_f16 MFMA epilogue, classic maps) + double-buffered
// Gh with G(bt+1) software-pipelined under MFMA(bt): one barrier per batch,
// G-phase global-load latency hidden under MFMA+stores.
__global__ __launch_bounds__(512, 4)
void dtn_mfma16p(const float* __restrict__ A, const float* __restrict__ Bf,
                 const float* __restrict__ C, const int* __restrict__ x,
                 float* __restrict__ out)
{
    __shared__ __align__(16) _Float16 A2c[8 * IPAD * 8];     // 49280 B
    __shared__ __align__(16) _Float16 Gh[2][64 * GSTR];      // 2 x 9216 B = 67712 total

    const int t = threadIdx.x;
    const long b0 = (long)blockIdx.x * 256;

    // ---- Stage A2c[(a*IPAD+i)*8+e] = f16(A[a*NR + i*8 + e]); 3072 chunks, 6 iters.
    #pragma unroll
    for (int it = 0; it < 6; ++it) {
        const int idx = t + it * 512;     // 0..3071
        const int i = idx >> 3;
        const int a = idx & 7;
        const float4* src = reinterpret_cast<const float4*>(A + (size_t)a * NR + (size_t)i * RR);
        const float4 f0 = src[0];
        const float4 f1 = src[1];
        half8v h;
        h[0] = (_Float16)f0.x; h[1] = (_Float16)f0.y; h[2] = (_Float16)f0.z; h[3] = (_Float16)f0.w;
        h[4] = (_Float16)f1.x; h[5] = (_Float16)f1.y; h[6] = (_Float16)f1.z; h[7] = (_Float16)f1.w;
        *reinterpret_cast<half8v*>(&A2c[(size_t)(a * IPAD + i) * 8]) = h;
    }

    const int gbl = t >> 3;      // G-phase: pair-in-batch
    const int ga  = t & 7;       // G-phase: a-column

    // ---- G(0) -> Gh[0]  (math identical to proven r10/r13)
    {
        const long pair = b0 + gbl;
        const int j = x[2 * pair];
        const int k = x[2 * pair + 1];
        const float* Bj = Bf + (size_t)j * RR;
        const float* Ck = C + (size_t)k * RR + ga;
        float ck[8];
        #pragma unroll
        for (int c = 0; c < 8; ++c)
            ck[c] = Ck[(size_t)c * NR];
        half8v h;
        #pragma unroll
        for (int b2 = 0; b2 < 8; ++b2) {
            const float4* br = reinterpret_cast<const float4*>(Bj + (size_t)b2 * NR);
            const float4 r0 = br[0];
            const float4 r1 = br[1];
            const float s = r0.x * ck[0] + r0.y * ck[1] + r0.z * ck[2] + r0.w * ck[3]
                          + r1.x * ck[4] + r1.y * ck[5] + r1.z * ck[6] + r1.w * ck[7];
            h[b2] = (_Float16)s;
        }
        *reinterpret_cast<half8v*>(&Gh[0][gbl * GSTR + ga * 8]) = h;
    }
    __syncthreads();   // staging + Gh[0] visible

    const int lane = t & 63;
    const int w    = t >> 6;     // wave 0..7
    const int mt   = w & 3;      // M-tile (16 pairs) within the 64-pair batch
    const int nh   = w >> 2;     // i-half: [0,192) or [192,384)
    const int a16  = lane & 15;
    const int q    = lane >> 4;  // 0..3

    #pragma unroll 1
    for (int bt = 0; bt < 4; ++bt) {
        // ---- Pipelined G(bt+1) -> Gh[(bt+1)&1]: loads issue here, hide under MFMA.
        if (bt < 3) {
            const long pair = b0 + (bt + 1) * 64 + gbl;
            const int j = x[2 * pair];
            const int k = x[2 * pair + 1];
            const float* Bj = Bf + (size_t)j * RR;
            const float* Ck = C + (size_t)k * RR + ga;
            float ck[8];
            #pragma unroll
            for (int c = 0; c < 8; ++c)
                ck[c] = Ck[(size_t)c * NR];
            half8v h;
            #pragma unroll
            for (int b2 = 0; b2 < 8; ++b2) {
                const float4* br = reinterpret_cast<const float4*>(Bj + (size_t)b2 * NR);
                const float4 r0 = br[0];
                const float4 r1 = br[1];
                const float s = r0.x * ck[0] + r0.y * ck[1] + r0.z * ck[2] + r0.w * ck[3]
                              + r1.x * ck[4] + r1.y * ck[5] + r1.z * ck[6] + r1.w * ck[7];
                h[b2] = (_Float16)s;
            }
            *reinterpret_cast<half8v*>(&Gh[(bt + 1) & 1][gbl * GSTR + ga * 8]) = h;
        }

        // ---- MFMA(bt) from Gh[bt&1] (independent of the G writes above).
        const _Float16* g = Gh[bt & 1];
        const half4v af0 = *reinterpret_cast<const half4v*>(&g[(mt * 16 + a16) * GSTR +  0 + 4 * q]);
        const half4v af1 = *reinterpret_cast<const half4v*>(&g[(mt * 16 + a16) * GSTR + 16 + 4 * q]);
        const half4v af2 = *reinterpret_cast<const half4v*>(&g[(mt * 16 + a16) * GSTR + 32 + 4 * q]);
        const half4v af3 = *reinterpret_cast<const half4v*>(&g[(mt * 16 + a16) * GSTR + 48 + 4 * q]);

        const long prow0 = b0 + bt * 64 + mt * 16 + 4 * q;

        #pragma unroll 2
        for (int nt = 0; nt < 12; ++nt) {
            const int col = nh * 192 + nt * 16 + a16;
            f32x4 acc = {0.f, 0.f, 0.f, 0.f};
            const half4v bf0 = *reinterpret_cast<const half4v*>(
                &A2c[(size_t)((0 + (q >> 1)) * IPAD + col) * 8 + 4 * (q & 1)]);
            acc = __builtin_amdgcn_mfma_f32_16x16x16f16(af0, bf0, acc, 0, 0, 0);
            const half4v bf1 = *reinterpret_cast<const half4v*>(
                &A2c[(size_t)((2 + (q >> 1)) * IPAD + col) * 8 + 4 * (q & 1)]);
            acc = __builtin_amdgcn_mfma_f32_16x16x16f16(af1, bf1, acc, 0, 0, 0);
            const half4v bf2 = *reinterpret_cast<const half4v*>(
                &A2c[(size_t)((4 + (q >> 1)) * IPAD + col) * 8 + 4 * (q & 1)]);
            acc = __builtin_amdgcn_mfma_f32_16x16x16f16(af2, bf2, acc, 0, 0, 0);
            const half4v bf3 = *reinterpret_cast<const half4v*>(
                &A2c[(size_t)((6 + (q >> 1)) * IPAD + col) * 8 + 4 * (q & 1)]);
            acc = __builtin_amdgcn_mfma_f32_16x16x16f16(af3, bf3, acc, 0, 0, 0);

            float* op = out + (size_t)prow0 * NN + col;
            op[0]            = acc[0];
            op[(size_t)NN]   = acc[1];
            op[(size_t)2*NN] = acc[2];
            op[(size_t)3*NN] = acc[3];
        }

        __syncthreads();   // Gh[(bt+1)&1] visible; Gh[bt&1] safe to rewrite at bt+2
    }
}

extern "C" void kernel_launch(void* const* d_in, const int* in_sizes, int n_in,
                              void* d_out, int out_size, void* d_ws, size_t ws_size,
                              hipStream_t stream) {
    const float* A  = (const float*)d_in[0];
    const float* Bf = (const float*)d_in[1];
    const float* C  = (const float*)d_in[2];
    const int*   x  = (const int*)d_in[3];
    float* out = (float*)d_out;
    const int B = in_sizes[3] / 2;           // 524288
    dtn_mfma16p<<<B / 256, 512, 0, stream>>>(A, Bf, C, x, out);
}